// Round 3
// baseline (249.620 us; speedup 1.0000x reference)
//
#include <hip/hip_runtime.h>

// GAT layer, N=8192, F_in=512, F_out=256.
// Pipeline: k_u (u=W^T a + zero denom/maxbits) -> k_rowvec (wh1,wh2,max)
//           -> k_wh (whT bf16 GEMM) -> k_attn (fused masked-softmax x wh, split-K=4,
//              2-deep prefetch pipeline) -> k_out (combine 4 partials + elu)

typedef __attribute__((ext_vector_type(8))) short short8;
typedef __attribute__((ext_vector_type(4))) float f32x4;

__device__ __forceinline__ unsigned short f2bf(float f) {
  unsigned int u = __float_as_uint(f);
  unsigned int r = u + 0x7FFFu + ((u >> 16) & 1u);  // RNE
  return (unsigned short)(r >> 16);
}

__device__ __forceinline__ unsigned fkey(float f) {  // order-preserving f32->u32
  int i = __float_as_int(f);
  return (i < 0) ? ~(unsigned)i : ((unsigned)i | 0x80000000u);
}

// ------- u1 = W^T a1, u2 = W^T a2 (512 each), atomic-free; also zero denom/maxbits -------
__global__ __launch_bounds__(512) void k_u(const float* __restrict__ W,
                                           const float* __restrict__ a1,
                                           const float* __restrict__ a2,
                                           float* __restrict__ u1,
                                           float* __restrict__ u2,
                                           float* __restrict__ denom,
                                           unsigned int* __restrict__ maxbits) {
  __shared__ float p1[16][32], p2[16][32];
  const int tid = threadIdx.x;
  const int gid = blockIdx.x * 512 + tid;
  denom[gid] = 0.f;  // grid 16 x 512 = 8192 == N
  if (gid == 0) *maxbits = 0u;
  const int kk = tid & 31, og = tid >> 5;  // k-slot 0..31, o-group 0..15
  const int k0 = blockIdx.x * 32;          // grid 16
  float s1 = 0.f, s2 = 0.f;
#pragma unroll
  for (int j = 0; j < 16; j++) {
    const int o = og * 16 + j;
    const float w = W[(size_t)o * 512 + k0 + kk];
    s1 += w * a1[o];
    s2 += w * a2[o];
  }
  p1[og][kk] = s1;
  p2[og][kk] = s2;
  __syncthreads();
  if (tid < 32) {
    float t1 = 0.f, t2 = 0.f;
#pragma unroll
    for (int g = 0; g < 16; g++) { t1 += p1[g][tid]; t2 += p2[g][tid]; }
    u1[k0 + tid] = t1;
    u2[k0 + tid] = t2;
  }
}

// ---------------- wh1[i]=h_i.u1, wh2[i]=h_i.u2, max(wh2) ----------------
__global__ __launch_bounds__(256) void k_rowvec(const float* __restrict__ h,
                                                const float* __restrict__ u1,
                                                const float* __restrict__ u2,
                                                float* __restrict__ wh1,
                                                float* __restrict__ wh2,
                                                unsigned int* __restrict__ maxbits) {
  __shared__ float su1[512], su2[512];
  const int tid = threadIdx.x;
  for (int i = tid; i < 512; i += 256) { su1[i] = u1[i]; su2[i] = u2[i]; }
  __syncthreads();
  const int lane = tid & 63;
  const int row = blockIdx.x * 4 + (tid >> 6);  // grid 2048 -> 8192 rows
  const float* hp = h + (size_t)row * 512 + lane * 8;
  float4 x0 = *(const float4*)hp;
  float4 x1 = *(const float4*)(hp + 4);
  const float* q1 = su1 + lane * 8;
  const float* q2 = su2 + lane * 8;
  float s1 = x0.x * q1[0] + x0.y * q1[1] + x0.z * q1[2] + x0.w * q1[3]
           + x1.x * q1[4] + x1.y * q1[5] + x1.z * q1[6] + x1.w * q1[7];
  float s2 = x0.x * q2[0] + x0.y * q2[1] + x0.z * q2[2] + x0.w * q2[3]
           + x1.x * q2[4] + x1.y * q2[5] + x1.z * q2[6] + x1.w * q2[7];
#pragma unroll
  for (int off = 32; off >= 1; off >>= 1) {
    s1 += __shfl_xor(s1, off);
    s2 += __shfl_xor(s2, off);
  }
  if (lane == 0) {
    wh1[row] = s1;
    wh2[row] = s2;
    atomicMax(maxbits, fkey(s2));
  }
}

// ---------------- whT[n][m] = (h @ W^T)[m][n] in bf16 (MFMA GEMM) ----------------
__global__ __launch_bounds__(512, 1) void k_wh(const float* __restrict__ h,
                                               const float* __restrict__ W,
                                               unsigned short* __restrict__ whT) {
  __shared__ uint4 lds[2560];  // h tile: 512 slots (8 KB) | W tile: 2048 slots (32 KB)
  const int tid = threadIdx.x;
  const int i0 = blockIdx.x * 64;  // grid 128
  const int lane = tid & 63, wid = tid >> 6;
  const int wm = wid >> 2, wn = wid & 3;
  const int l16 = lane & 15, lq = lane >> 4;
  const int hr = tid >> 3, hc = tid & 7;  // h staging: row 0..63, slot 0..7
  const int wr = tid >> 1, wc = tid & 1;  // W staging: row 0..255, half

  f32x4 acc[2][4] = {};

  for (int t = 0; t < 8; t++) {
    const int k0 = t * 64;
    const float* hp = h + (size_t)(i0 + hr) * 512 + k0 + hc * 8;
    float4 hx = *(const float4*)hp;
    float4 hy = *(const float4*)(hp + 4);
    const float* wp = W + (size_t)wr * 512 + k0 + wc * 32;
    float4 wv[8];
#pragma unroll
    for (int q = 0; q < 8; q++) wv[q] = *(const float4*)(wp + q * 4);

    __syncthreads();  // previous round's MFMA reads done
    uint4 hw;
    hw.x = (unsigned)f2bf(hx.x) | ((unsigned)f2bf(hx.y) << 16);
    hw.y = (unsigned)f2bf(hx.z) | ((unsigned)f2bf(hx.w) << 16);
    hw.z = (unsigned)f2bf(hy.x) | ((unsigned)f2bf(hy.y) << 16);
    hw.w = (unsigned)f2bf(hy.z) | ((unsigned)f2bf(hy.w) << 16);
    lds[hr * 8 + (hc ^ (hr & 7))] = hw;
#pragma unroll
    for (int q = 0; q < 4; q++) {
      uint4 ww;
      ww.x = (unsigned)f2bf(wv[2 * q].x) | ((unsigned)f2bf(wv[2 * q].y) << 16);
      ww.y = (unsigned)f2bf(wv[2 * q].z) | ((unsigned)f2bf(wv[2 * q].w) << 16);
      ww.z = (unsigned)f2bf(wv[2 * q + 1].x) | ((unsigned)f2bf(wv[2 * q + 1].y) << 16);
      ww.w = (unsigned)f2bf(wv[2 * q + 1].z) | ((unsigned)f2bf(wv[2 * q + 1].w) << 16);
      lds[512 + wr * 8 + ((wc * 4 + q) ^ (wr & 7))] = ww;
    }
    __syncthreads();
#pragma unroll
    for (int ks = 0; ks < 2; ks++) {
      const int r0 = wm * 32 + l16, r1 = r0 + 16;
      short8 fa0 = *(const short8*)&lds[r0 * 8 + ((ks * 4 + lq) ^ (r0 & 7))];
      short8 fa1 = *(const short8*)&lds[r1 * 8 + ((ks * 4 + lq) ^ (r1 & 7))];
#pragma unroll
      for (int fn = 0; fn < 4; fn++) {
        const int bn = wn * 64 + fn * 16 + l16;
        short8 fb = *(const short8*)&lds[512 + bn * 8 + ((ks * 4 + lq) ^ (bn & 7))];
        acc[0][fn] = __builtin_amdgcn_mfma_f32_16x16x32_bf16(fa0, fb, acc[0][fn], 0, 0, 0);
        acc[1][fn] = __builtin_amdgcn_mfma_f32_16x16x32_bf16(fa1, fb, acc[1][fn], 0, 0, 0);
      }
    }
  }
  // epilogue: whT[n][m], pack 4 consecutive m as bf16
#pragma unroll
  for (int fm = 0; fm < 2; fm++) {
#pragma unroll
    for (int fn = 0; fn < 4; fn++) {
      const int n = wn * 64 + fn * 16 + l16;
      const int m0 = i0 + wm * 32 + fm * 16 + lq * 4;
      uint2 o;
      o.x = (unsigned)f2bf(acc[fm][fn][0]) | ((unsigned)f2bf(acc[fm][fn][1]) << 16);
      o.y = (unsigned)f2bf(acc[fm][fn][2]) | ((unsigned)f2bf(acc[fm][fn][3]) << 16);
      *(uint2*)(whT + (size_t)n * 8192 + m0) = o;
    }
  }
}

// ---------------- fused masked softmax-numerator x wh, 2-deep prefetch ----------------
// grid 512 = 128 row-blocks (BM=64) x 4 K-splits (2048 j each); BK=64/round, 32 rounds.
struct StageRegs {
  int4 qa, qb;
  float4 za, zb;
  uint4 v0, v1, v2, v3;
};

__global__ __launch_bounds__(512, 2) void k_attn(
    const int* __restrict__ adj, const unsigned short* __restrict__ whT,
    const float* __restrict__ wh1, const float* __restrict__ wh2,
    const unsigned int* __restrict__ maxbits,
    float* __restrict__ out0, float* __restrict__ out1,
    float* __restrict__ out2, float* __restrict__ out3,
    float* __restrict__ denom) {
  __shared__ uint4 lds[5120];  // 2 x (P: 512 slots | whT: 2048 slots) = 80 KB
  const int NT = 32;           // rounds per split
  const int tid = threadIdx.x;
  const int bid = blockIdx.x;
  const int mb = bid & 127, sb = bid >> 7;  // sb 0..3
  const int i0 = mb * 64;
  const int jbase = sb * 2048;

  const unsigned int mk = *maxbits;
  const float wh2max =
      __uint_as_float((mk & 0x80000000u) ? (mk & 0x7FFFFFFFu) : ~mk);

  const int pr = tid >> 3, pc = tid & 7;  // P staging: row 0..63, slot 0..7
  const int wr = tid >> 1, wc = tid & 1;  // whT staging: row 0..255, half
  const float wh1r = wh1[i0 + pr];
  const float tm = wh1r + wh2max;
  const float Mi = tm > 0.f ? tm : 0.2f * tm;  // exact per-row softmax shift bound

  const int* adjp = adj + (size_t)(i0 + pr) * 8192 + jbase + pc * 8;
  const float* wh2p = wh2 + jbase + pc * 8;
  const unsigned short* whp = whT + (size_t)wr * 8192 + jbase + wc * 32;

  const int lane = tid & 63, wid = tid >> 6;
  const int wm = wid >> 2, wn = wid & 3;
  const int l16 = lane & 15, lq = lane >> 4;

  f32x4 acc[2][4] = {};
  float dsum = 0.f;
  StageRegs GA, GB;

// issue global loads for round T into reg set R (T>=NT -> harmless dummy re-read of 0)
#define ISSUE(R, T)                                      \
  do {                                                   \
    const int o_ = (((T) < NT) ? (T) : 0) * 64;          \
    R.qa = *(const int4*)(adjp + o_);                    \
    R.qb = *(const int4*)(adjp + o_ + 4);                \
    R.za = *(const float4*)(wh2p + o_);                  \
    R.zb = *(const float4*)(wh2p + o_ + 4);              \
    R.v0 = *(const uint4*)(whp + o_);                    \
    R.v1 = *(const uint4*)(whp + o_ + 8);                \
    R.v2 = *(const uint4*)(whp + o_ + 16);               \
    R.v3 = *(const uint4*)(whp + o_ + 24);               \
  } while (0)

// exp+pack reg set R, write into LDS buffer at slot-offset BASE
#define CONSUME(R, BASE)                                                     \
  do {                                                                       \
    int av[8] = {R.qa.x, R.qa.y, R.qa.z, R.qa.w, R.qb.x, R.qb.y, R.qb.z, R.qb.w}; \
    float zv[8] = {R.za.x, R.za.y, R.za.z, R.za.w, R.zb.x, R.zb.y, R.zb.z, R.zb.w}; \
    float pv[8];                                                             \
    _Pragma("unroll") for (int i = 0; i < 8; i++) {                          \
      float x = wh1r + zv[i];                                                \
      float e = x > 0.f ? x : 0.2f * x;                                      \
      float p = (av[i] > 0) ? __expf(e - Mi) : 0.f;                          \
      pv[i] = p;                                                             \
      dsum += p;                                                             \
    }                                                                        \
    uint4 pw;                                                                \
    pw.x = (unsigned)f2bf(pv[0]) | ((unsigned)f2bf(pv[1]) << 16);            \
    pw.y = (unsigned)f2bf(pv[2]) | ((unsigned)f2bf(pv[3]) << 16);            \
    pw.z = (unsigned)f2bf(pv[4]) | ((unsigned)f2bf(pv[5]) << 16);            \
    pw.w = (unsigned)f2bf(pv[6]) | ((unsigned)f2bf(pv[7]) << 16);            \
    lds[(BASE) + pr * 8 + (pc ^ (pr & 7))] = pw;                             \
    lds[(BASE) + 512 + wr * 8 + ((wc * 4 + 0) ^ (wr & 7))] = R.v0;           \
    lds[(BASE) + 512 + wr * 8 + ((wc * 4 + 1) ^ (wr & 7))] = R.v1;           \
    lds[(BASE) + 512 + wr * 8 + ((wc * 4 + 2) ^ (wr & 7))] = R.v2;           \
    lds[(BASE) + 512 + wr * 8 + ((wc * 4 + 3) ^ (wr & 7))] = R.v3;           \
  } while (0)

// MFMA phase reading LDS buffer at slot-offset BASE
#define MFMA_PH(BASE)                                                        \
  do {                                                                       \
    _Pragma("unroll") for (int ks = 0; ks < 2; ks++) {                       \
      const int r0 = wm * 32 + l16, r1 = r0 + 16;                            \
      short8 fa0 = *(const short8*)&lds[(BASE) + r0 * 8 + ((ks * 4 + lq) ^ (r0 & 7))]; \
      short8 fa1 = *(const short8*)&lds[(BASE) + r1 * 8 + ((ks * 4 + lq) ^ (r1 & 7))]; \
      _Pragma("unroll") for (int fn = 0; fn < 4; fn++) {                     \
        const int bn = wn * 64 + fn * 16 + l16;                              \
        short8 fb = *(const short8*)&lds[(BASE) + 512 + bn * 8 + ((ks * 4 + lq) ^ (bn & 7))]; \
        acc[0][fn] = __builtin_amdgcn_mfma_f32_16x16x32_bf16(fa0, fb, acc[0][fn], 0, 0, 0); \
        acc[1][fn] = __builtin_amdgcn_mfma_f32_16x16x32_bf16(fa1, fb, acc[1][fn], 0, 0, 0); \
      }                                                                      \
    }                                                                        \
  } while (0)

  // prologue: rounds 0,1 issued; round 0 staged into buf0; round 2 issued
  ISSUE(GA, 0);
  ISSUE(GB, 1);
  CONSUME(GA, 0);
  __syncthreads();
  ISSUE(GA, 2);
  MFMA_PH(0);        // round 0
  CONSUME(GB, 2560); // stage round 1 -> buf1
  __syncthreads();

  for (int t2 = 1; t2 + 1 < NT; t2 += 2) {
    // round t2 (odd): reads buf1
    ISSUE(GB, t2 + 2);
    MFMA_PH(2560);
    CONSUME(GA, 0);  // stage round t2+1 -> buf0
    __syncthreads();
    // round t2+1 (even): reads buf0
    ISSUE(GA, t2 + 3);
    MFMA_PH(0);
    CONSUME(GB, 2560);  // stage round t2+2 -> buf1
    __syncthreads();
  }
  MFMA_PH(2560);  // round NT-1

#undef ISSUE
#undef CONSUME
#undef MFMA_PH

  // write split partials (sb=0 -> d_out used as scratch, else ws)
  float* outp = (sb == 0) ? out0 : (sb == 1) ? out1 : (sb == 2) ? out2 : out3;
#pragma unroll
  for (int fm = 0; fm < 2; fm++) {
#pragma unroll
    for (int fn = 0; fn < 4; fn++) {
      const int col = wn * 64 + fn * 16 + l16;
      const int row0 = i0 + wm * 32 + fm * 16 + lq * 4;
#pragma unroll
      for (int r = 0; r < 4; r++)
        outp[(size_t)(row0 + r) * 256 + col] = acc[fm][fn][r];
    }
  }

  // denom: 8 lanes per row hold partials
  dsum += __shfl_xor(dsum, 1);
  dsum += __shfl_xor(dsum, 2);
  dsum += __shfl_xor(dsum, 4);
  if ((tid & 7) == 0) atomicAdd(denom + i0 + pr, dsum);
}

// ---------------- combine split-K partials, divide by denom, elu ----------------
__global__ __launch_bounds__(256) void k_out(float* __restrict__ out,
                                             const float* __restrict__ p1,
                                             const float* __restrict__ p2,
                                             const float* __restrict__ p3,
                                             const float* __restrict__ denom) {
  const int idx = blockIdx.x * 256 + threadIdx.x;  // grid 2048, 1 float4 each
  float4 o = ((const float4*)out)[idx];
  float4 a = ((const float4*)p1)[idx];
  float4 b = ((const float4*)p2)[idx];
  float4 c = ((const float4*)p3)[idx];
  const float inv = 1.0f / denom[idx >> 6];
  float v0 = (o.x + a.x + b.x + c.x) * inv;
  float v1 = (o.y + a.y + b.y + c.y) * inv;
  float v2 = (o.z + a.z + b.z + c.z) * inv;
  float v3 = (o.w + a.w + b.w + c.w) * inv;
  v0 = v0 > 0.f ? v0 : expm1f(v0);
  v1 = v1 > 0.f ? v1 : expm1f(v1);
  v2 = v2 > 0.f ? v2 : expm1f(v2);
  v3 = v3 > 0.f ? v3 : expm1f(v3);
  ((float4*)out)[idx] = make_float4(v0, v1, v2, v3);
}

extern "C" void kernel_launch(void* const* d_in, const int* in_sizes, int n_in,
                              void* d_out, int out_size, void* d_ws, size_t ws_size,
                              hipStream_t stream) {
  const float* h = (const float*)d_in[0];
  const float* W = (const float*)d_in[1];
  const float* a1 = (const float*)d_in[2];
  const float* a2 = (const float*)d_in[3];
  const int* adj = (const int*)d_in[4];
  float* out = (float*)d_out;
  char* ws = (char*)d_ws;

  // ws layout: [whT 4MB][p1 8MB][p2 8MB][p3 8MB][wh1 32K][wh2 32K][denom 32K][u1 2K][u2 2K][maxbits]
  unsigned short* whT = (unsigned short*)ws;
  float* part1 = (float*)(ws + (4u << 20));
  float* part2 = (float*)(ws + (12u << 20));
  float* part3 = (float*)(ws + (20u << 20));
  float* wh1 = (float*)(ws + (28u << 20));
  float* wh2 = wh1 + 8192;
  float* denom = wh2 + 8192;
  float* u1 = denom + 8192;
  float* u2 = u1 + 512;
  unsigned int* maxbits = (unsigned int*)(u2 + 512);

  hipLaunchKernelGGL(k_u, dim3(16), dim3(512), 0, stream, W, a1, a2, u1, u2,
                     denom, maxbits);
  hipLaunchKernelGGL(k_rowvec, dim3(2048), dim3(256), 0, stream, h, u1, u2, wh1,
                     wh2, maxbits);
  hipLaunchKernelGGL(k_wh, dim3(128), dim3(512), 0, stream, h, W, whT);
  hipLaunchKernelGGL(k_attn, dim3(512), dim3(512), 0, stream, adj, whT, wh1,
                     wh2, maxbits, out, part1, part2, part3, denom);
  hipLaunchKernelGGL(k_out, dim3(2048), dim3(256), 0, stream, out, part1, part2,
                     part3, denom);
  (void)in_sizes; (void)n_in; (void)out_size; (void)ws_size;
}

// Round 4
// 205.628 us; speedup vs baseline: 1.2139x; 1.2139x over previous
//
#include <hip/hip_runtime.h>

// GAT layer, N=8192, F_in=512, F_out=256.
// Pipeline: k_mask (adj -> 8MB bitmask) -> k_u (u=W^T a) -> k_rowvec (wh1,wh2,blockmax)
//           -> k_max (global max) -> k_wh (whT bf16 GEMM) -> k_attn (fused masked
//           softmax-numerator x wh, split-K=4, L2-resident inputs) -> k_out (combine+elu)

typedef __attribute__((ext_vector_type(8))) short short8;
typedef __attribute__((ext_vector_type(4))) float f32x4;

__device__ __forceinline__ unsigned short f2bf(float f) {
  unsigned int u = __float_as_uint(f);
  unsigned int r = u + 0x7FFFu + ((u >> 16) & 1u);  // RNE
  return (unsigned short)(r >> 16);
}

// ---------------- adj (int32 0/1) -> bitmask, one wave per row ----------------
__global__ __launch_bounds__(256) void k_mask(const int* __restrict__ adj,
                                              unsigned long long* __restrict__ bm) {
  const int row = blockIdx.x * 4 + (threadIdx.x >> 6);  // grid 2048
  const int lane = threadIdx.x & 63;
  const int* ap = adj + (size_t)row * 8192 + lane;
  unsigned long long* bp = bm + (size_t)row * 128;
#pragma unroll 2
  for (int c = 0; c < 128; c += 4) {
    int v0 = ap[(c + 0) * 64];
    int v1 = ap[(c + 1) * 64];
    int v2 = ap[(c + 2) * 64];
    int v3 = ap[(c + 3) * 64];
    unsigned long long m0 = __ballot(v0 > 0);
    unsigned long long m1 = __ballot(v1 > 0);
    unsigned long long m2 = __ballot(v2 > 0);
    unsigned long long m3 = __ballot(v3 > 0);
    if (lane == 0) {
      *(ulonglong2*)(bp + c) = make_ulonglong2(m0, m1);
      *(ulonglong2*)(bp + c + 2) = make_ulonglong2(m2, m3);
    }
  }
}

// ---------------- u1 = W^T a1, u2 = W^T a2 (512 each), atomic-free ----------------
__global__ __launch_bounds__(512) void k_u(const float* __restrict__ W,
                                           const float* __restrict__ a1,
                                           const float* __restrict__ a2,
                                           float* __restrict__ u1,
                                           float* __restrict__ u2) {
  __shared__ float p1[16][32], p2[16][32];
  const int tid = threadIdx.x;
  const int kk = tid & 31, og = tid >> 5;  // k-slot 0..31, o-group 0..15
  const int k0 = blockIdx.x * 32;          // grid 16
  float s1 = 0.f, s2 = 0.f;
#pragma unroll
  for (int j = 0; j < 16; j++) {
    const int o = og * 16 + j;
    const float w = W[(size_t)o * 512 + k0 + kk];
    s1 += w * a1[o];
    s2 += w * a2[o];
  }
  p1[og][kk] = s1;
  p2[og][kk] = s2;
  __syncthreads();
  if (tid < 32) {
    float t1 = 0.f, t2 = 0.f;
#pragma unroll
    for (int g = 0; g < 16; g++) { t1 += p1[g][tid]; t2 += p2[g][tid]; }
    u1[k0 + tid] = t1;
    u2[k0 + tid] = t2;
  }
}

// ------- wh1[i]=h_i.u1, wh2[i]=h_i.u2, per-block max(wh2) (no global atomics) -------
__global__ __launch_bounds__(256) void k_rowvec(const float* __restrict__ h,
                                                const float* __restrict__ u1,
                                                const float* __restrict__ u2,
                                                float* __restrict__ wh1,
                                                float* __restrict__ wh2,
                                                float* __restrict__ pmax) {
  __shared__ float su1[512], su2[512];
  __shared__ float smax[4];
  const int tid = threadIdx.x;
  for (int i = tid; i < 512; i += 256) { su1[i] = u1[i]; su2[i] = u2[i]; }
  __syncthreads();
  const int lane = tid & 63;
  const int row = blockIdx.x * 4 + (tid >> 6);  // grid 2048 -> 8192 rows
  const float* hp = h + (size_t)row * 512 + lane * 8;
  float4 x0 = *(const float4*)hp;
  float4 x1 = *(const float4*)(hp + 4);
  const float* q1 = su1 + lane * 8;
  const float* q2 = su2 + lane * 8;
  float s1 = x0.x * q1[0] + x0.y * q1[1] + x0.z * q1[2] + x0.w * q1[3]
           + x1.x * q1[4] + x1.y * q1[5] + x1.z * q1[6] + x1.w * q1[7];
  float s2 = x0.x * q2[0] + x0.y * q2[1] + x0.z * q2[2] + x0.w * q2[3]
           + x1.x * q2[4] + x1.y * q2[5] + x1.z * q2[6] + x1.w * q2[7];
#pragma unroll
  for (int off = 32; off >= 1; off >>= 1) {
    s1 += __shfl_xor(s1, off);
    s2 += __shfl_xor(s2, off);
  }
  if (lane == 0) {
    wh1[row] = s1;
    wh2[row] = s2;
    smax[tid >> 6] = s2;
  }
  __syncthreads();
  if (tid == 0)
    pmax[blockIdx.x] = fmaxf(fmaxf(smax[0], smax[1]), fmaxf(smax[2], smax[3]));
}

// ---------------- reduce pmax[2048] -> gmax (single block) ----------------
__global__ __launch_bounds__(256) void k_max(const float* __restrict__ pmax,
                                             float* __restrict__ gmax) {
  __shared__ float sm[4];
  const int tid = threadIdx.x;
  float m = -3.0e38f;
  for (int i = tid; i < 2048; i += 256) m = fmaxf(m, pmax[i]);
#pragma unroll
  for (int off = 32; off >= 1; off >>= 1) m = fmaxf(m, __shfl_xor(m, off));
  if ((tid & 63) == 0) sm[tid >> 6] = m;
  __syncthreads();
  if (tid == 0) gmax[0] = fmaxf(fmaxf(sm[0], sm[1]), fmaxf(sm[2], sm[3]));
}

// ---------------- whT[n][m] = (h @ W^T)[m][n] in bf16 (MFMA GEMM) ----------------
__global__ __launch_bounds__(512, 1) void k_wh(const float* __restrict__ h,
                                               const float* __restrict__ W,
                                               unsigned short* __restrict__ whT) {
  __shared__ uint4 lds[2560];  // h tile: 512 slots (8 KB) | W tile: 2048 slots (32 KB)
  const int tid = threadIdx.x;
  const int i0 = blockIdx.x * 64;  // grid 128
  const int lane = tid & 63, wid = tid >> 6;
  const int wm = wid >> 2, wn = wid & 3;
  const int l16 = lane & 15, lq = lane >> 4;
  const int hr = tid >> 3, hc = tid & 7;  // h staging: row 0..63, slot 0..7
  const int wr = tid >> 1, wc = tid & 1;  // W staging: row 0..255, half

  f32x4 acc[2][4] = {};

  for (int t = 0; t < 8; t++) {
    const int k0 = t * 64;
    const float* hp = h + (size_t)(i0 + hr) * 512 + k0 + hc * 8;
    float4 hx = *(const float4*)hp;
    float4 hy = *(const float4*)(hp + 4);
    const float* wp = W + (size_t)wr * 512 + k0 + wc * 32;
    float4 wv[8];
#pragma unroll
    for (int q = 0; q < 8; q++) wv[q] = *(const float4*)(wp + q * 4);

    __syncthreads();  // previous round's MFMA reads done
    uint4 hw;
    hw.x = (unsigned)f2bf(hx.x) | ((unsigned)f2bf(hx.y) << 16);
    hw.y = (unsigned)f2bf(hx.z) | ((unsigned)f2bf(hx.w) << 16);
    hw.z = (unsigned)f2bf(hy.x) | ((unsigned)f2bf(hy.y) << 16);
    hw.w = (unsigned)f2bf(hy.z) | ((unsigned)f2bf(hy.w) << 16);
    lds[hr * 8 + (hc ^ (hr & 7))] = hw;
#pragma unroll
    for (int q = 0; q < 4; q++) {
      uint4 ww;
      ww.x = (unsigned)f2bf(wv[2 * q].x) | ((unsigned)f2bf(wv[2 * q].y) << 16);
      ww.y = (unsigned)f2bf(wv[2 * q].z) | ((unsigned)f2bf(wv[2 * q].w) << 16);
      ww.z = (unsigned)f2bf(wv[2 * q + 1].x) | ((unsigned)f2bf(wv[2 * q + 1].y) << 16);
      ww.w = (unsigned)f2bf(wv[2 * q + 1].z) | ((unsigned)f2bf(wv[2 * q + 1].w) << 16);
      lds[512 + wr * 8 + ((wc * 4 + q) ^ (wr & 7))] = ww;
    }
    __syncthreads();
#pragma unroll
    for (int ks = 0; ks < 2; ks++) {
      const int r0 = wm * 32 + l16, r1 = r0 + 16;
      short8 fa0 = *(const short8*)&lds[r0 * 8 + ((ks * 4 + lq) ^ (r0 & 7))];
      short8 fa1 = *(const short8*)&lds[r1 * 8 + ((ks * 4 + lq) ^ (r1 & 7))];
#pragma unroll
      for (int fn = 0; fn < 4; fn++) {
        const int bn = wn * 64 + fn * 16 + l16;
        short8 fb = *(const short8*)&lds[512 + bn * 8 + ((ks * 4 + lq) ^ (bn & 7))];
        acc[0][fn] = __builtin_amdgcn_mfma_f32_16x16x32_bf16(fa0, fb, acc[0][fn], 0, 0, 0);
        acc[1][fn] = __builtin_amdgcn_mfma_f32_16x16x32_bf16(fa1, fb, acc[1][fn], 0, 0, 0);
      }
    }
  }
  // epilogue: whT[n][m], pack 4 consecutive m as bf16
#pragma unroll
  for (int fm = 0; fm < 2; fm++) {
#pragma unroll
    for (int fn = 0; fn < 4; fn++) {
      const int n = wn * 64 + fn * 16 + l16;
      const int m0 = i0 + wm * 32 + fm * 16 + lq * 4;
      uint2 o;
      o.x = (unsigned)f2bf(acc[fm][fn][0]) | ((unsigned)f2bf(acc[fm][fn][1]) << 16);
      o.y = (unsigned)f2bf(acc[fm][fn][2]) | ((unsigned)f2bf(acc[fm][fn][3]) << 16);
      *(uint2*)(whT + (size_t)n * 8192 + m0) = o;
    }
  }
}

// ---------------- fused masked softmax-numerator x wh (bitmask inputs) ----------------
// grid 512 = 128 row-blocks (BM=64) x 4 K-splits (2048 j each); BK=64/round, 32 rounds.
struct StageRegs {
  unsigned long long bmv;
  float4 za, zb;
  uint4 v0, v1, v2, v3;
};

__global__ __launch_bounds__(512, 4) void k_attn(
    const unsigned long long* __restrict__ bm, const unsigned short* __restrict__ whT,
    const float* __restrict__ wh1, const float* __restrict__ wh2,
    const float* __restrict__ gmax,
    float* __restrict__ out0, float* __restrict__ out1,
    float* __restrict__ out2, float* __restrict__ out3,
    float* __restrict__ denp) {
  __shared__ uint4 lds[5120];  // 2 x (P: 512 slots | whT: 2048 slots) = 80 KB
  const int NT = 32;           // rounds per split
  const int tid = threadIdx.x;
  const int bid = blockIdx.x;
  const int mb = bid & 127, sb = bid >> 7;  // sb 0..3
  const int i0 = mb * 64;
  const int jbase = sb * 2048;

  const float wh2max = gmax[0];

  const int pr = tid >> 3, pc = tid & 7;  // P staging: row 0..63, slot 0..7
  const int wr = tid >> 1, wc = tid & 1;  // whT staging: row 0..255, half
  const float wh1r = wh1[i0 + pr];
  const float tm = wh1r + wh2max;
  const float Mi = tm > 0.f ? tm : 0.2f * tm;  // exact per-row softmax shift bound

  const unsigned long long* bmp = bm + (size_t)(i0 + pr) * 128 + sb * 32;
  const float* wh2p = wh2 + jbase + pc * 8;
  const unsigned short* whp = whT + (size_t)wr * 8192 + jbase + wc * 32;

  const int lane = tid & 63, wid = tid >> 6;
  const int wm = wid >> 2, wn = wid & 3;
  const int l16 = lane & 15, lq = lane >> 4;

  f32x4 acc[2][4] = {};
  float dsum = 0.f;
  StageRegs GA, GB;

// issue global loads for round T into reg set R (T>=NT -> harmless dummy re-read of 0)
#define ISSUE(R, T)                                      \
  do {                                                   \
    const int t_ = ((T) < NT) ? (T) : 0;                 \
    const int o_ = t_ * 64;                              \
    R.bmv = bmp[t_];                                     \
    R.za = *(const float4*)(wh2p + o_);                  \
    R.zb = *(const float4*)(wh2p + o_ + 4);              \
    R.v0 = *(const uint4*)(whp + o_);                    \
    R.v1 = *(const uint4*)(whp + o_ + 8);                \
    R.v2 = *(const uint4*)(whp + o_ + 16);               \
    R.v3 = *(const uint4*)(whp + o_ + 24);               \
  } while (0)

// exp+pack reg set R, write into LDS buffer at slot-offset BASE
#define CONSUME(R, BASE)                                                     \
  do {                                                                       \
    const unsigned long long mv = R.bmv >> (pc * 8);                         \
    float zv[8] = {R.za.x, R.za.y, R.za.z, R.za.w, R.zb.x, R.zb.y, R.zb.z, R.zb.w}; \
    float pv[8];                                                             \
    _Pragma("unroll") for (int i = 0; i < 8; i++) {                          \
      float x = wh1r + zv[i];                                                \
      float e = x > 0.f ? x : 0.2f * x;                                      \
      float p = ((mv >> i) & 1ull) ? __expf(e - Mi) : 0.f;                   \
      pv[i] = p;                                                             \
      dsum += p;                                                             \
    }                                                                        \
    uint4 pw;                                                                \
    pw.x = (unsigned)f2bf(pv[0]) | ((unsigned)f2bf(pv[1]) << 16);            \
    pw.y = (unsigned)f2bf(pv[2]) | ((unsigned)f2bf(pv[3]) << 16);            \
    pw.z = (unsigned)f2bf(pv[4]) | ((unsigned)f2bf(pv[5]) << 16);            \
    pw.w = (unsigned)f2bf(pv[6]) | ((unsigned)f2bf(pv[7]) << 16);            \
    lds[(BASE) + pr * 8 + (pc ^ (pr & 7))] = pw;                             \
    lds[(BASE) + 512 + wr * 8 + ((wc * 4 + 0) ^ (wr & 7))] = R.v0;           \
    lds[(BASE) + 512 + wr * 8 + ((wc * 4 + 1) ^ (wr & 7))] = R.v1;           \
    lds[(BASE) + 512 + wr * 8 + ((wc * 4 + 2) ^ (wr & 7))] = R.v2;           \
    lds[(BASE) + 512 + wr * 8 + ((wc * 4 + 3) ^ (wr & 7))] = R.v3;           \
  } while (0)

// MFMA phase reading LDS buffer at slot-offset BASE
#define MFMA_PH(BASE)                                                        \
  do {                                                                       \
    _Pragma("unroll") for (int ks = 0; ks < 2; ks++) {                       \
      const int r0 = wm * 32 + l16, r1 = r0 + 16;                            \
      short8 fa0 = *(const short8*)&lds[(BASE) + r0 * 8 + ((ks * 4 + lq) ^ (r0 & 7))]; \
      short8 fa1 = *(const short8*)&lds[(BASE) + r1 * 8 + ((ks * 4 + lq) ^ (r1 & 7))]; \
      _Pragma("unroll") for (int fn = 0; fn < 4; fn++) {                     \
        const int bn = wn * 64 + fn * 16 + l16;                              \
        short8 fb = *(const short8*)&lds[(BASE) + 512 + bn * 8 + ((ks * 4 + lq) ^ (bn & 7))]; \
        acc[0][fn] = __builtin_amdgcn_mfma_f32_16x16x32_bf16(fa0, fb, acc[0][fn], 0, 0, 0); \
        acc[1][fn] = __builtin_amdgcn_mfma_f32_16x16x32_bf16(fa1, fb, acc[1][fn], 0, 0, 0); \
      }                                                                      \
    }                                                                        \
  } while (0)

  // prologue: rounds 0,1 issued; round 0 staged into buf0; round 2 issued
  ISSUE(GA, 0);
  ISSUE(GB, 1);
  CONSUME(GA, 0);
  __syncthreads();
  ISSUE(GA, 2);
  MFMA_PH(0);        // round 0
  CONSUME(GB, 2560); // stage round 1 -> buf1
  __syncthreads();

  for (int t2 = 1; t2 + 1 < NT; t2 += 2) {
    // round t2 (odd): reads buf1
    ISSUE(GB, t2 + 2);
    MFMA_PH(2560);
    CONSUME(GA, 0);  // stage round t2+1 -> buf0
    __syncthreads();
    // round t2+1 (even): reads buf0
    ISSUE(GA, t2 + 3);
    MFMA_PH(0);
    CONSUME(GB, 2560);  // stage round t2+2 -> buf1
    __syncthreads();
  }
  MFMA_PH(2560);  // round NT-1

#undef ISSUE
#undef CONSUME
#undef MFMA_PH

  // write split partials (sb=0 -> d_out used as scratch, else ws)
  float* outp = (sb == 0) ? out0 : (sb == 1) ? out1 : (sb == 2) ? out2 : out3;
#pragma unroll
  for (int fm = 0; fm < 2; fm++) {
#pragma unroll
    for (int fn = 0; fn < 4; fn++) {
      const int col = wn * 64 + fn * 16 + l16;
      const int row0 = i0 + wm * 32 + fm * 16 + lq * 4;
#pragma unroll
      for (int r = 0; r < 4; r++)
        outp[(size_t)(row0 + r) * 256 + col] = acc[fm][fn][r];
    }
  }

  // denom: 8 lanes per row hold partials; write per-split slice (no atomics)
  dsum += __shfl_xor(dsum, 1);
  dsum += __shfl_xor(dsum, 2);
  dsum += __shfl_xor(dsum, 4);
  if ((tid & 7) == 0) denp[sb * 8192 + i0 + pr] = dsum;
}

// ---------------- combine split-K partials, divide by denom, elu ----------------
__global__ __launch_bounds__(256) void k_out(float* __restrict__ out,
                                             const float* __restrict__ p1,
                                             const float* __restrict__ p2,
                                             const float* __restrict__ p3,
                                             const float* __restrict__ denp) {
  const int idx = blockIdx.x * 256 + threadIdx.x;  // grid 2048, 1 float4 each
  const int row = idx >> 6;
  float4 o = ((const float4*)out)[idx];
  float4 a = ((const float4*)p1)[idx];
  float4 b = ((const float4*)p2)[idx];
  float4 c = ((const float4*)p3)[idx];
  const float inv =
      1.0f / (denp[row] + denp[8192 + row] + denp[16384 + row] + denp[24576 + row]);
  float v0 = (o.x + a.x + b.x + c.x) * inv;
  float v1 = (o.y + a.y + b.y + c.y) * inv;
  float v2 = (o.z + a.z + b.z + c.z) * inv;
  float v3 = (o.w + a.w + b.w + c.w) * inv;
  v0 = v0 > 0.f ? v0 : expm1f(v0);
  v1 = v1 > 0.f ? v1 : expm1f(v1);
  v2 = v2 > 0.f ? v2 : expm1f(v2);
  v3 = v3 > 0.f ? v3 : expm1f(v3);
  ((float4*)out)[idx] = make_float4(v0, v1, v2, v3);
}

extern "C" void kernel_launch(void* const* d_in, const int* in_sizes, int n_in,
                              void* d_out, int out_size, void* d_ws, size_t ws_size,
                              hipStream_t stream) {
  const float* h = (const float*)d_in[0];
  const float* W = (const float*)d_in[1];
  const float* a1 = (const float*)d_in[2];
  const float* a2 = (const float*)d_in[3];
  const int* adj = (const int*)d_in[4];
  float* out = (float*)d_out;
  char* ws = (char*)d_ws;

  // ws: [whT 4MB][p1 8MB][p2 8MB][p3 8MB][bm 8MB][denp 128K][wh1][wh2][pmax][u1][u2][gmax]
  unsigned short* whT = (unsigned short*)ws;
  float* part1 = (float*)(ws + (4u << 20));
  float* part2 = (float*)(ws + (12u << 20));
  float* part3 = (float*)(ws + (20u << 20));
  unsigned long long* bm = (unsigned long long*)(ws + (28u << 20));
  float* denp = (float*)(ws + (36u << 20));  // 4*8192
  float* wh1 = denp + 4 * 8192;
  float* wh2 = wh1 + 8192;
  float* pmax = wh2 + 8192;  // 2048
  float* u1 = pmax + 2048;
  float* u2 = u1 + 512;
  float* gmax = u2 + 512;

  hipLaunchKernelGGL(k_mask, dim3(2048), dim3(256), 0, stream, adj, bm);
  hipLaunchKernelGGL(k_u, dim3(16), dim3(512), 0, stream, W, a1, a2, u1, u2);
  hipLaunchKernelGGL(k_rowvec, dim3(2048), dim3(256), 0, stream, h, u1, u2, wh1,
                     wh2, pmax);
  hipLaunchKernelGGL(k_max, dim3(1), dim3(256), 0, stream, pmax, gmax);
  hipLaunchKernelGGL(k_wh, dim3(128), dim3(512), 0, stream, h, W, whT);
  hipLaunchKernelGGL(k_attn, dim3(512), dim3(512), 0, stream, bm, whT, wh1,
                     wh2, gmax, out, part1, part2, part3, denp);
  hipLaunchKernelGGL(k_out, dim3(2048), dim3(256), 0, stream, out, part1, part2,
                     part3, denp);
  (void)in_sizes; (void)n_in; (void)out_size; (void)ws_size;
}

// Round 5
// 145.892 us; speedup vs baseline: 1.7110x; 1.4095x over previous
//
#include <hip/hip_runtime.h>

// GAT layer, N=8192, F_in=512, F_out=256.
// Pipeline: k_u -> k_rowvec (wh1,wh2,blockmax) -> k_max -> k_wh (whT bf16 GEMM)
//   -> k_attn (streams adj directly; P-in-registers; whT via global_load_lds ring;
//      one raw barrier/round with counted-vmcnt fence; split-K=4)
//   -> k_out (combine 4 partials + elu)

typedef __attribute__((ext_vector_type(8))) short short8;
typedef __attribute__((ext_vector_type(4))) float f32x4;

__device__ __forceinline__ unsigned short f2bf(float f) {
  unsigned int u = __float_as_uint(f);
  unsigned int r = u + 0x7FFFu + ((u >> 16) & 1u);  // RNE
  return (unsigned short)(r >> 16);
}

// ---------------- u1 = W^T a1, u2 = W^T a2 (512 each), atomic-free ----------------
__global__ __launch_bounds__(512) void k_u(const float* __restrict__ W,
                                           const float* __restrict__ a1,
                                           const float* __restrict__ a2,
                                           float* __restrict__ u1,
                                           float* __restrict__ u2) {
  __shared__ float p1[16][32], p2[16][32];
  const int tid = threadIdx.x;
  const int kk = tid & 31, og = tid >> 5;
  const int k0 = blockIdx.x * 32;  // grid 16
  float s1 = 0.f, s2 = 0.f;
#pragma unroll
  for (int j = 0; j < 16; j++) {
    const int o = og * 16 + j;
    const float w = W[(size_t)o * 512 + k0 + kk];
    s1 += w * a1[o];
    s2 += w * a2[o];
  }
  p1[og][kk] = s1;
  p2[og][kk] = s2;
  __syncthreads();
  if (tid < 32) {
    float t1 = 0.f, t2 = 0.f;
#pragma unroll
    for (int g = 0; g < 16; g++) { t1 += p1[g][tid]; t2 += p2[g][tid]; }
    u1[k0 + tid] = t1;
    u2[k0 + tid] = t2;
  }
}

// ------- wh1[i]=h_i.u1, wh2[i]=h_i.u2, per-block max(wh2) (no global atomics) -------
__global__ __launch_bounds__(256) void k_rowvec(const float* __restrict__ h,
                                                const float* __restrict__ u1,
                                                const float* __restrict__ u2,
                                                float* __restrict__ wh1,
                                                float* __restrict__ wh2,
                                                float* __restrict__ pmax) {
  __shared__ float su1[512], su2[512];
  __shared__ float smax[4];
  const int tid = threadIdx.x;
  for (int i = tid; i < 512; i += 256) { su1[i] = u1[i]; su2[i] = u2[i]; }
  __syncthreads();
  const int lane = tid & 63;
  const int row = blockIdx.x * 4 + (tid >> 6);  // grid 2048
  const float* hp = h + (size_t)row * 512 + lane * 8;
  float4 x0 = *(const float4*)hp;
  float4 x1 = *(const float4*)(hp + 4);
  const float* q1 = su1 + lane * 8;
  const float* q2 = su2 + lane * 8;
  float s1 = x0.x * q1[0] + x0.y * q1[1] + x0.z * q1[2] + x0.w * q1[3]
           + x1.x * q1[4] + x1.y * q1[5] + x1.z * q1[6] + x1.w * q1[7];
  float s2 = x0.x * q2[0] + x0.y * q2[1] + x0.z * q2[2] + x0.w * q2[3]
           + x1.x * q2[4] + x1.y * q2[5] + x1.z * q2[6] + x1.w * q2[7];
#pragma unroll
  for (int off = 32; off >= 1; off >>= 1) {
    s1 += __shfl_xor(s1, off);
    s2 += __shfl_xor(s2, off);
  }
  if (lane == 0) {
    wh1[row] = s1;
    wh2[row] = s2;
    smax[tid >> 6] = s2;
  }
  __syncthreads();
  if (tid == 0)
    pmax[blockIdx.x] = fmaxf(fmaxf(smax[0], smax[1]), fmaxf(smax[2], smax[3]));
}

// ---------------- reduce pmax[2048] -> gmax ----------------
__global__ __launch_bounds__(256) void k_max(const float* __restrict__ pmax,
                                             float* __restrict__ gmax) {
  __shared__ float sm[4];
  const int tid = threadIdx.x;
  float m = -3.0e38f;
  for (int i = tid; i < 2048; i += 256) m = fmaxf(m, pmax[i]);
#pragma unroll
  for (int off = 32; off >= 1; off >>= 1) m = fmaxf(m, __shfl_xor(m, off));
  if ((tid & 63) == 0) sm[tid >> 6] = m;
  __syncthreads();
  if (tid == 0) gmax[0] = fmaxf(fmaxf(sm[0], sm[1]), fmaxf(sm[2], sm[3]));
}

// ---------------- whT[n][m] = (h @ W^T)[m][n] in bf16 (MFMA GEMM) ----------------
__global__ __launch_bounds__(512, 1) void k_wh(const float* __restrict__ h,
                                               const float* __restrict__ W,
                                               unsigned short* __restrict__ whT) {
  __shared__ uint4 lds[2560];
  const int tid = threadIdx.x;
  const int i0 = blockIdx.x * 64;  // grid 128
  const int lane = tid & 63, wid = tid >> 6;
  const int wm = wid >> 2, wn = wid & 3;
  const int l16 = lane & 15, lq = lane >> 4;
  const int hr = tid >> 3, hc = tid & 7;
  const int wr = tid >> 1, wc = tid & 1;

  f32x4 acc[2][4] = {};

  for (int t = 0; t < 8; t++) {
    const int k0 = t * 64;
    const float* hp = h + (size_t)(i0 + hr) * 512 + k0 + hc * 8;
    float4 hx = *(const float4*)hp;
    float4 hy = *(const float4*)(hp + 4);
    const float* wp = W + (size_t)wr * 512 + k0 + wc * 32;
    float4 wv[8];
#pragma unroll
    for (int q = 0; q < 8; q++) wv[q] = *(const float4*)(wp + q * 4);

    __syncthreads();
    uint4 hw;
    hw.x = (unsigned)f2bf(hx.x) | ((unsigned)f2bf(hx.y) << 16);
    hw.y = (unsigned)f2bf(hx.z) | ((unsigned)f2bf(hx.w) << 16);
    hw.z = (unsigned)f2bf(hy.x) | ((unsigned)f2bf(hy.y) << 16);
    hw.w = (unsigned)f2bf(hy.z) | ((unsigned)f2bf(hy.w) << 16);
    lds[hr * 8 + (hc ^ (hr & 7))] = hw;
#pragma unroll
    for (int q = 0; q < 4; q++) {
      uint4 ww;
      ww.x = (unsigned)f2bf(wv[2 * q].x) | ((unsigned)f2bf(wv[2 * q].y) << 16);
      ww.y = (unsigned)f2bf(wv[2 * q].z) | ((unsigned)f2bf(wv[2 * q].w) << 16);
      ww.z = (unsigned)f2bf(wv[2 * q + 1].x) | ((unsigned)f2bf(wv[2 * q + 1].y) << 16);
      ww.w = (unsigned)f2bf(wv[2 * q + 1].z) | ((unsigned)f2bf(wv[2 * q + 1].w) << 16);
      lds[512 + wr * 8 + ((wc * 4 + q) ^ (wr & 7))] = ww;
    }
    __syncthreads();
#pragma unroll
    for (int ks = 0; ks < 2; ks++) {
      const int r0 = wm * 32 + l16, r1 = r0 + 16;
      short8 fa0 = *(const short8*)&lds[r0 * 8 + ((ks * 4 + lq) ^ (r0 & 7))];
      short8 fa1 = *(const short8*)&lds[r1 * 8 + ((ks * 4 + lq) ^ (r1 & 7))];
#pragma unroll
      for (int fn = 0; fn < 4; fn++) {
        const int bn = wn * 64 + fn * 16 + l16;
        short8 fb = *(const short8*)&lds[512 + bn * 8 + ((ks * 4 + lq) ^ (bn & 7))];
        acc[0][fn] = __builtin_amdgcn_mfma_f32_16x16x32_bf16(fa0, fb, acc[0][fn], 0, 0, 0);
        acc[1][fn] = __builtin_amdgcn_mfma_f32_16x16x32_bf16(fa1, fb, acc[1][fn], 0, 0, 0);
      }
    }
  }
#pragma unroll
  for (int fm = 0; fm < 2; fm++) {
#pragma unroll
    for (int fn = 0; fn < 4; fn++) {
      const int n = wn * 64 + fn * 16 + l16;
      const int m0 = i0 + wm * 32 + fm * 16 + lq * 4;
      uint2 o;
      o.x = (unsigned)f2bf(acc[fm][fn][0]) | ((unsigned)f2bf(acc[fm][fn][1]) << 16);
      o.y = (unsigned)f2bf(acc[fm][fn][2]) | ((unsigned)f2bf(acc[fm][fn][3]) << 16);
      *(uint2*)(whT + (size_t)n * 8192 + m0) = o;
    }
  }
}

// ---------------- fused masked softmax-numerator x wh, P-in-registers ----------------
// grid 256 = 64 row-blocks (BM=128) x 4 K-splits (2048 j each); BK=64, NT=32 rounds.
struct PFR {
  int4 a0, a1, a2, a3;     // adj[row][j-slices]
  float4 z0, z1, z2, z3;   // wh2[j-slices]
};

__global__ __launch_bounds__(512, 2) void k_attn(
    const int* __restrict__ adj, const unsigned short* __restrict__ whT,
    const float* __restrict__ wh1, const float* __restrict__ wh2,
    const float* __restrict__ gmax,
    float* __restrict__ out0, float* __restrict__ out1,
    float* __restrict__ out2, float* __restrict__ out3,
    float* __restrict__ denp) {
  __shared__ uint4 lds_t[3 * 2048];  // 3-slot ring of whT tiles [256 n][64 j] bf16, 96 KB
  const int NT = 32;
  const int tid = threadIdx.x;
  const int bid = blockIdx.x;
  // XCD-clustered mapping: blocks on one XCD share the same sb (whT slice L2-resident)
  const int sb = (bid & 7) >> 1;                     // 0..3
  const int mb = ((bid >> 3) << 1) | (bid & 1);      // 0..63
  const int i0 = mb * 128;
  const int jbase = sb * 2048;
  const int lane = tid & 63, w = tid >> 6;
  const int l16 = lane & 15, q = lane >> 4;
  const int row_a = i0 + w * 16 + l16;

  const float wh2max = gmax[0];
  const float wh1r = wh1[row_a];
  const float tm = wh1r + wh2max;
  const float Mi = tm > 0.f ? tm : 0.2f * tm;  // exact per-row softmax shift bound

  const int* adjp = adj + (size_t)row_a * 8192 + jbase + q * 8;
  const float* wh2p = wh2 + jbase + q * 8;

  f32x4 acc[16] = {};
  float dsum = 0.f;
  short8 pa0, pa1;
  PFR PA, PB;

// stage whT tile for round TT into ring slot SLOT via global_load_lds.
// LDS linear slot L holds global chunk at in-row byte (subL*16)^((row&7)<<4)
#define STAGE(TT, SLOT)                                                        \
  do {                                                                         \
    const int tt_ = ((TT) < NT) ? (TT) : 0;                                    \
    const size_t gj_ = (size_t)(jbase + tt_ * 64);                             \
    _Pragma("unroll") for (int qq = 0; qq < 4; qq++) {                         \
      const int L = qq * 512 + tid;                                            \
      const int row = L >> 3, sub = L & 7;                                     \
      const int boff = (sub * 16) ^ ((row & 7) << 4);                          \
      const char* src_ =                                                       \
          (const char*)(whT + (size_t)row * 8192 + gj_) + boff;                \
      char* dst_ = (char*)lds_t + (SLOT) * 32768 + L * 16;                     \
      __builtin_amdgcn_global_load_lds(                                        \
          (const __attribute__((address_space(1))) unsigned int*)src_,         \
          (__attribute__((address_space(3))) unsigned int*)dst_, 16, 0, 0);    \
    }                                                                          \
  } while (0)

#define PFLOAD(R, T)                                    \
  do {                                                  \
    const int o_ = (((T) < NT) ? (T) : 0) * 64;         \
    R.a0 = *(const int4*)(adjp + o_);                   \
    R.a1 = *(const int4*)(adjp + o_ + 4);               \
    R.a2 = *(const int4*)(adjp + o_ + 32);              \
    R.a3 = *(const int4*)(adjp + o_ + 36);              \
    R.z0 = *(const float4*)(wh2p + o_);                 \
    R.z1 = *(const float4*)(wh2p + o_ + 4);             \
    R.z2 = *(const float4*)(wh2p + o_ + 32);            \
    R.z3 = *(const float4*)(wh2p + o_ + 36);            \
  } while (0)

// compute 16 P values (this lane's row, its j-slices) -> A-frags pa0 (ks0), pa1 (ks1)
#define COMPUTE(R)                                                             \
  do {                                                                         \
    int av[16] = {R.a0.x, R.a0.y, R.a0.z, R.a0.w, R.a1.x, R.a1.y, R.a1.z,      \
                  R.a1.w, R.a2.x, R.a2.y, R.a2.z, R.a2.w, R.a3.x, R.a3.y,      \
                  R.a3.z, R.a3.w};                                             \
    float zv[16] = {R.z0.x, R.z0.y, R.z0.z, R.z0.w, R.z1.x, R.z1.y, R.z1.z,    \
                    R.z1.w, R.z2.x, R.z2.y, R.z2.z, R.z2.w, R.z3.x, R.z3.y,    \
                    R.z3.z, R.z3.w};                                           \
    float pv[16];                                                              \
    _Pragma("unroll") for (int i = 0; i < 16; i++) {                           \
      float x = wh1r + zv[i];                                                  \
      float e = x > 0.f ? x : 0.2f * x;                                        \
      float p = (av[i] > 0) ? __expf(e - Mi) : 0.f;                            \
      pv[i] = p;                                                               \
      dsum += p;                                                               \
    }                                                                          \
    _Pragma("unroll") for (int i = 0; i < 8; i++) {                            \
      pa0[i] = (short)f2bf(pv[i]);                                             \
      pa1[i] = (short)f2bf(pv[8 + i]);                                         \
    }                                                                          \
  } while (0)

// counted-vmcnt fence (memory clobber pins PF loads before, ds_reads after)
#define FENCE_BAR                                        \
  do {                                                   \
    asm volatile("s_waitcnt vmcnt(12)" ::: "memory");    \
    __builtin_amdgcn_s_barrier();                        \
  } while (0)

#define MFMAPH(SLOT)                                                           \
  do {                                                                         \
    const char* lb_ = (const char*)lds_t + (SLOT) * 32768;                     \
    _Pragma("unroll") for (int nb = 0; nb < 16; nb++) {                        \
      const int n_ = nb * 16 + l16;                                            \
      const int rb_ = n_ * 128;                                                \
      const int sw_ = (n_ & 7) << 4;                                           \
      short8 fb0 = *(const short8*)(lb_ + rb_ + ((q * 16) ^ sw_));             \
      short8 fb1 = *(const short8*)(lb_ + rb_ + ((64 + q * 16) ^ sw_));        \
      acc[nb] = __builtin_amdgcn_mfma_f32_16x16x32_bf16(pa0, fb0, acc[nb], 0, 0, 0); \
      acc[nb] = __builtin_amdgcn_mfma_f32_16x16x32_bf16(pa1, fb1, acc[nb], 0, 0, 0); \
    }                                                                          \
  } while (0)

  // prologue
  STAGE(0, 0);
  STAGE(1, 1);
  PFLOAD(PA, 0);

  int sA = 0, sB = 1, sC = 2;  // ring slots of rounds t, t+1, t+2
  for (int t = 0; t < NT; t += 2) {
    // round t (even)
    PFLOAD(PB, t + 1);
    COMPUTE(PA);
    FENCE_BAR;
    STAGE(t + 2, sC);
    MFMAPH(sA);
    // round t+1 (odd)
    PFLOAD(PA, t + 2);
    COMPUTE(PB);
    FENCE_BAR;
    STAGE(t + 3, sA);
    MFMAPH(sB);
    int tmp = sA; sA = sC; sC = sB; sB = tmp;
  }

#undef STAGE
#undef PFLOAD
#undef COMPUTE
#undef FENCE_BAR
#undef MFMAPH

  // epilogue: D rows = q*4+r within the wave's 16, cols = nb*16+l16
  float* outp = (sb == 0) ? out0 : (sb == 1) ? out1 : (sb == 2) ? out2 : out3;
  const int r0 = i0 + w * 16 + q * 4;
#pragma unroll
  for (int nb = 0; nb < 16; nb++) {
    const int col = nb * 16 + l16;
#pragma unroll
    for (int r = 0; r < 4; r++)
      outp[(size_t)(r0 + r) * 256 + col] = acc[nb][r];
  }

  // denom: lane holds row l16's partial over its j-quarter; reduce across q
  dsum += __shfl_xor(dsum, 16);
  dsum += __shfl_xor(dsum, 32);
  if (lane < 16) denp[sb * 8192 + i0 + w * 16 + lane] = dsum;
}

// ---------------- combine split-K partials, divide by denom, elu ----------------
__global__ __launch_bounds__(256) void k_out(float* __restrict__ out,
                                             const float* __restrict__ p1,
                                             const float* __restrict__ p2,
                                             const float* __restrict__ p3,
                                             const float* __restrict__ denp) {
  const int idx = blockIdx.x * 256 + threadIdx.x;  // grid 2048
  const int row = idx >> 6;
  float4 o = ((const float4*)out)[idx];
  float4 a = ((const float4*)p1)[idx];
  float4 b = ((const float4*)p2)[idx];
  float4 c = ((const float4*)p3)[idx];
  const float inv =
      1.0f / (denp[row] + denp[8192 + row] + denp[16384 + row] + denp[24576 + row]);
  float v0 = (o.x + a.x + b.x + c.x) * inv;
  float v1 = (o.y + a.y + b.y + c.y) * inv;
  float v2 = (o.z + a.z + b.z + c.z) * inv;
  float v3 = (o.w + a.w + b.w + c.w) * inv;
  v0 = v0 > 0.f ? v0 : expm1f(v0);
  v1 = v1 > 0.f ? v1 : expm1f(v1);
  v2 = v2 > 0.f ? v2 : expm1f(v2);
  v3 = v3 > 0.f ? v3 : expm1f(v3);
  ((float4*)out)[idx] = make_float4(v0, v1, v2, v3);
}

extern "C" void kernel_launch(void* const* d_in, const int* in_sizes, int n_in,
                              void* d_out, int out_size, void* d_ws, size_t ws_size,
                              hipStream_t stream) {
  const float* h = (const float*)d_in[0];
  const float* W = (const float*)d_in[1];
  const float* a1 = (const float*)d_in[2];
  const float* a2 = (const float*)d_in[3];
  const int* adj = (const int*)d_in[4];
  float* out = (float*)d_out;
  char* ws = (char*)d_ws;

  // ws: [whT 4MB][p1 8MB][p2 8MB][p3 8MB][denp 128K][wh1][wh2][pmax][u1][u2][gmax]
  unsigned short* whT = (unsigned short*)ws;
  float* part1 = (float*)(ws + (4u << 20));
  float* part2 = (float*)(ws + (12u << 20));
  float* part3 = (float*)(ws + (20u << 20));
  float* denp = (float*)(ws + (28u << 20));  // 4*8192
  float* wh1 = denp + 4 * 8192;
  float* wh2 = wh1 + 8192;
  float* pmax = wh2 + 8192;  // 2048
  float* u1 = pmax + 2048;
  float* u2 = u1 + 512;
  float* gmax = u2 + 512;

  hipLaunchKernelGGL(k_u, dim3(16), dim3(512), 0, stream, W, a1, a2, u1, u2);
  hipLaunchKernelGGL(k_rowvec, dim3(2048), dim3(256), 0, stream, h, u1, u2, wh1,
                     wh2, pmax);
  hipLaunchKernelGGL(k_max, dim3(1), dim3(256), 0, stream, pmax, gmax);
  hipLaunchKernelGGL(k_wh, dim3(128), dim3(512), 0, stream, h, W, whT);
  hipLaunchKernelGGL(k_attn, dim3(256), dim3(512), 0, stream, adj, whT, wh1,
                     wh2, gmax, out, part1, part2, part3, denp);
  hipLaunchKernelGGL(k_out, dim3(2048), dim3(256), 0, stream, out, part1, part2,
                     part3, denp);
  (void)in_sizes; (void)n_in; (void)out_size; (void)ws_size;
}